// Round 11
// baseline (150.217 us; speedup 1.0000x reference)
//
#include <hip/hip_runtime.h>

#define T_LEN 2048
#define NCHUNK 16
#define CH 128        // steps per block
#define HALF 64       // steps per wave (store/fused range)
#define WARM 64       // warm-up steps (10.7*mu)
#define RK 16         // renorm every 16 steps (scale cancels in LLR)

// ---- DPP helpers (VALU pipe). ctrl is a compile-time constant. ----
template <int CTRL>
__device__ __forceinline__ float dpp_add(float v) {
    int r = __builtin_amdgcn_update_dpp(0, __float_as_int(v), CTRL, 0xF, 0xF, true);
    return v + __int_as_float(r);
}
// Sum of all 64 lanes, valid in lane 63.
__device__ __forceinline__ float red63(float v) {
    v = dpp_add<0x111>(v);   // row_shr 1
    v = dpp_add<0x112>(v);   // row_shr 2
    v = dpp_add<0x114>(v);   // row_shr 4
    v = dpp_add<0x118>(v);   // row_shr 8
    v = dpp_add<0x142>(v);   // row_bcast15
    v = dpp_add<0x143>(v);   // row_bcast31
    return v;
}
// Half sums: lane31 = sum(lanes 0..31), lane63 = sum(lanes 32..63).
__device__ __forceinline__ float red_half(float v) {
    v = dpp_add<0x111>(v);
    v = dpp_add<0x112>(v);
    v = dpp_add<0x114>(v);
    v = dpp_add<0x118>(v);
    v = dpp_add<0x142>(v);
    return v;
}
__device__ __forceinline__ float rdlane(float v, int l) {
    return __uint_as_float(__builtin_amdgcn_readlane(__float_as_uint(v), l));
}
__device__ __forceinline__ float bcast63(float v) { return rdlane(v, 63); }
__device__ __forceinline__ float pair_sum_xor1(float v) { return dpp_add<0xB1>(v); }
__device__ __forceinline__ unsigned short bf16_of(float f) {
    return (unsigned short)((__float_as_uint(f) + 0x8000u) >> 16);
}

// GEN_POLY = ('1111001','1011011'), mu=6, NS=64. State s: shift reg, newest bit = MSB.
// o0 parity mask 57, o1 mask 27. log2-domain branch metric:
// x_s = kE*la + (kE*c0)*l0 + (kE*c1)*l1, kE = 0.5*log2(e); gamma(s,0)=2^x_s, gamma(s,1)=2^-x_s.
//
// One block per (b, chunk): symmetric two-wave split.
// Phase 1 (beta): wave0 sweeps down to t0+64 storing LDS rows [64,128);
//                 wave1 sweeps down to t0 storing rows [0,64). 128 steps each.
// Phase 2 (alpha+LLR): wave0 warm+fused over [t0, t0+64) (reads wave1's rows);
//                      wave1 over [t0+64, t0+128) (reads wave0's rows). 128 steps each.
// LLR flow identity: an[j] = pre-norm alpha_{t+1}[j] collects b=0 flow for j<32,
// b=1 for j>=32:  n0 = sum_{j<32} an[j]*beta_{t+1}[j], n1 = sum_{j>=32} (...).
__global__ __launch_bounds__(128, 5)
void bcjr_one(const float* __restrict__ llr_ch,   // [B][2*T]
              const float* __restrict__ llr_a,    // [B][T]
              float* __restrict__ out)            // [B][T]
{
    __shared__ unsigned short lds_b[CH * 64];     // row r = bf16 beta_{t0+r+1}[lane]

    const int blk   = blockIdx.x;
    const int b     = blk >> 4;                   // NCHUNK = 16
    const int chunk = blk & (NCHUNK - 1);
    const int wave  = threadIdx.x >> 6;
    const int lane  = threadIdx.x & 63;
    const int t0    = chunk * CH;

    const float c0 = 1.0f - 2.0f * (float)(__popc(lane & 57) & 1);
    const float c1 = 1.0f - 2.0f * (float)(__popc(lane & 27) & 1);
    const float kE = 0.5f * 1.442695040888963f;
    const float k0 = kE * c0, k1 = kE * c1;
    const float LN2 = 0.69314718055994531f;

    const float* chp = llr_ch + (size_t)b * (2 * T_LEN);
    const float* lap = llr_a  + (size_t)b * T_LEN;

    // ================= phase 1: beta halves -> LDS =================
    {
        const int sbeg = wave ? t0 : (t0 + HALF);         // store range [sbeg, sbeg+64)
        // last chunk, wave0: starts at T with EXACT uniform beta_T (no warm needed)
        const int hi = (wave == 0 && chunk == NCHUNK - 1) ? (t0 + CH)
                                                          : (sbeg + HALF + WARM);
        const int bs0 = lane >> 1, bs1 = 32 + (lane >> 1);
        float state = 1.0f / 64.0f;

        for (int g = hi - RK; g >= sbeg; g -= RK) {
            #pragma unroll
            for (int h = 1; h >= 0; --h) {
                const int gb = g + 8 * h;
                const float4* c4 = (const float4*)(chp + 2 * gb);
                const float4* a4 = (const float4*)(lap + gb);
                float4 cc[4], aa[2];
                #pragma unroll
                for (int i = 0; i < 4; ++i) cc[i] = c4[i];
                #pragma unroll
                for (int i = 0; i < 2; ++i) aa[i] = a4[i];
                #pragma unroll
                for (int i = 7; i >= 0; --i) {
                    const int t = gb + i;
                    float l0 = (i & 1) ? cc[i >> 1].z : cc[i >> 1].x;
                    float l1 = (i & 1) ? cc[i >> 1].w : cc[i >> 1].y;
                    float la = ((const float*)aa)[i];
                    if (t < sbeg + HALF)
                        lds_b[(t - t0) * 64 + lane] = bf16_of(state);   // beta_{t+1}
                    float x   = fmaf(la, kE, fmaf(l0, k0, l1 * k1));
                    float g0v = exp2f(x);
                    float g1v = __builtin_amdgcn_rcpf(g0v);
                    float t0v = __shfl(state, bs0, 64);
                    float t1v = __shfl(state, bs1, 64);
                    state = fmaf(g0v, t0v, g1v * t1v);
                }
            }
            float s = bcast63(red63(state));
            state = state * __builtin_amdgcn_rcpf(s);
        }
    }

    __syncthreads();   // beta tile complete

    // ================= phase 2: alpha + fused LLR =================
    {
        const int fbeg = wave ? (t0 + HALF) : t0;   // fused range [fbeg, fbeg+64)
        int ts = fbeg - WARM;
        float state;
        if (ts <= 0) { ts = 0; state = (lane == 0) ? 1.0f : 0.0f; }  // exact at seq start
        else         { state = 1.0f / 64.0f; }
        const int  fs0 = 2 * (lane & 31);
        const bool fhi = (lane >= 32);

        // ---- warm-up: light alpha steps ----
        for (int g = ts; g < fbeg; g += RK) {
            #pragma unroll
            for (int h = 0; h < 2; ++h) {
                const int gb = g + 8 * h;
                const float4* c4 = (const float4*)(chp + 2 * gb);
                const float4* a4 = (const float4*)(lap + gb);
                float4 cc[4], aa[2];
                #pragma unroll
                for (int i = 0; i < 4; ++i) cc[i] = c4[i];
                #pragma unroll
                for (int i = 0; i < 2; ++i) aa[i] = a4[i];
                #pragma unroll
                for (int i = 0; i < 8; ++i) {
                    float l0 = (i & 1) ? cc[i >> 1].z : cc[i >> 1].x;
                    float l1 = (i & 1) ? cc[i >> 1].w : cc[i >> 1].y;
                    float la = ((const float*)aa)[i];
                    float x   = fmaf(la, kE, fmaf(l0, k0, l1 * k1));
                    float g0v = exp2f(x);
                    float g1v = __builtin_amdgcn_rcpf(g0v);
                    float s0  = pair_sum_xor1(state * g0v);
                    float s1  = pair_sum_xor1(state * g1v);
                    float a0  = __shfl(s0, fs0, 64);
                    float a1  = __shfl(s1, fs0, 64);
                    state = fhi ? a1 : a0;
                }
            }
            float s = bcast63(red63(state));
            state = state * __builtin_amdgcn_rcpf(s);
        }

        // ---- fused: alpha step + LLR emission (beta from LDS) ----
        float keep = 0.0f;
        for (int g = fbeg; g < fbeg + HALF; g += RK) {
            #pragma unroll
            for (int h = 0; h < 2; ++h) {
                const int gb = g + 8 * h;
                const float4* c4 = (const float4*)(chp + 2 * gb);
                const float4* a4 = (const float4*)(lap + gb);
                float4 cc[4], aa[2];
                #pragma unroll
                for (int i = 0; i < 4; ++i) cc[i] = c4[i];
                #pragma unroll
                for (int i = 0; i < 2; ++i) aa[i] = a4[i];
                unsigned short bu[8];
                #pragma unroll
                for (int i = 0; i < 8; ++i)
                    bu[i] = lds_b[(gb - t0 + i) * 64 + lane];   // beta_{t+1}[lane]
                #pragma unroll
                for (int i = 0; i < 8; ++i) {
                    const int t = gb + i;
                    float l0 = (i & 1) ? cc[i >> 1].z : cc[i >> 1].x;
                    float l1 = (i & 1) ? cc[i >> 1].w : cc[i >> 1].y;
                    float la = ((const float*)aa)[i];
                    float x   = fmaf(la, kE, fmaf(l0, k0, l1 * k1));
                    float g0v = exp2f(x);
                    float g1v = __builtin_amdgcn_rcpf(g0v);
                    float ag0 = state * g0v;
                    float ag1 = state * g1v;
                    float s0  = pair_sum_xor1(ag0);
                    float s1  = pair_sum_xor1(ag1);
                    float a0  = __shfl(s0, fs0, 64);
                    float a1  = __shfl(s1, fs0, 64);
                    float an  = fhi ? a1 : a0;              // alpha_{t+1}, pre-norm
                    float bv  = __uint_as_float(((unsigned)bu[i]) << 16);
                    float v   = red_half(an * bv);          // lane31=n0, lane63=n1
                    float n0  = rdlane(v, 31);
                    float n1  = rdlane(v, 63);
                    float llr = LN2 * __log2f(n0 * __builtin_amdgcn_rcpf(n1));
                    keep = (lane == (t & 63)) ? llr : keep;
                    state = an;
                }
            }
            float s = bcast63(red63(state));
            state = state * __builtin_amdgcn_rcpf(s);
        }
        out[(size_t)b * T_LEN + fbeg + lane] = keep;   // 64 llrs, coalesced
    }
}

extern "C" void kernel_launch(void* const* d_in, const int* in_sizes, int n_in,
                              void* d_out, int out_size, void* d_ws, size_t ws_size,
                              hipStream_t stream) {
    const float* llr_ch = (const float*)d_in[0];
    const float* llr_a  = (const float*)d_in[1];
    float* out = (float*)d_out;

    int B = in_sizes[0] / (2 * T_LEN);   // 256
    hipLaunchKernelGGL(bcjr_one, dim3(B * NCHUNK), dim3(128), 0, stream,
                       llr_ch, llr_a, out);
}